// Round 4
// baseline (742.775 us; speedup 1.0000x reference)
//
#include <hip/hip_runtime.h>
#include <hip/hip_bf16.h>

// MultiHeadAttentionBlock: B=2, S=4096, D=512, H=8, DK=64.
// fp32 in/out, bf16 MFMA compute, fp32 accumulation.
// cvt weights->bf16; 3x proj GEMM (Q,K head-split; V transposed);
// flash attention (swapped-operand QK^T and PV: softmax fully lane-local,
// 4 shuffles/tile instead of 32); out proj.

typedef __bf16 bf16_t;
typedef __bf16 bf16x8 __attribute__((ext_vector_type(8)));
typedef __bf16 bf16x4 __attribute__((ext_vector_type(4)));
typedef float f32x4 __attribute__((ext_vector_type(4)));

#define S_LEN 4096
#define NH 8
#define DK 64
#define DMODEL 512
#define NB 2

__device__ inline bf16x8 frag8(const bf16_t* p) {
  return *reinterpret_cast<const bf16x8*>(p);
}
__device__ inline bf16x8 frag8(const float* p) {
  f32x4 a = *reinterpret_cast<const f32x4*>(p);
  f32x4 b = *reinterpret_cast<const f32x4*>(p + 4);
  bf16x8 r;
#pragma unroll
  for (int j = 0; j < 4; ++j) { r[j] = (__bf16)a[j]; r[j + 4] = (__bf16)b[j]; }
  return r;
}

// ---------------------------------------------------------------------------
// One-time fp32 -> bf16 weight conversion. grid (256, 4), 4 elems/thread.
// ---------------------------------------------------------------------------
__global__ __launch_bounds__(256) void cvt_weights(
    const float* __restrict__ w0, const float* __restrict__ w1,
    const float* __restrict__ w2, const float* __restrict__ w3,
    bf16_t* __restrict__ o0, bf16_t* __restrict__ o1,
    bf16_t* __restrict__ o2, bf16_t* __restrict__ o3)
{
  const float* src = blockIdx.y == 0 ? w0 : blockIdx.y == 1 ? w1
                   : blockIdx.y == 2 ? w2 : w3;
  bf16_t* dst = blockIdx.y == 0 ? o0 : blockIdx.y == 1 ? o1
              : blockIdx.y == 2 ? o2 : o3;
  const int i = (blockIdx.x * 256 + threadIdx.x) * 4;
  f32x4 v = *reinterpret_cast<const f32x4*>(src + i);
  bf16x4 r;
#pragma unroll
  for (int j = 0; j < 4; ++j) r[j] = (__bf16)v[j];
  *reinterpret_cast<bf16x4*>(dst + i) = r;
}

// ---------------------------------------------------------------------------
// GEMM: out[m][n] = sum_k X[m][k] * W[n][k] + bias[n]
// M=8192, N=512, K=512. Tile 64x64/block, wave -> 16(m) x 64(n). W pre-cvt bf16.
// mode 0: out [B*H][S][DK]; mode 2: [B*H][DK][S] (V transposed); mode 1: [m][n].
// ---------------------------------------------------------------------------
template <typename TA, typename TO>
__global__ __launch_bounds__(256) void gemm_proj(
    const TA* __restrict__ X, const bf16_t* __restrict__ W,
    const float* __restrict__ bias, TO* __restrict__ out, int mode)
{
  const int mtile = blockIdx.x * 64;
  const int ntile = blockIdx.y * 64;
  const int wave = threadIdx.x >> 6;
  const int lane = threadIdx.x & 63;
  const int l16 = lane & 15;
  const int g = lane >> 4;
  const int m0 = mtile + wave * 16;

  f32x4 acc[4];
#pragma unroll
  for (int nb = 0; nb < 4; ++nb) acc[nb] = (f32x4){0.f, 0.f, 0.f, 0.f};

  const TA* xrow = X + (size_t)(m0 + l16) * DMODEL + g * 8;
  const bf16_t* wbase = W + (size_t)(ntile + l16) * DMODEL + g * 8;

#pragma unroll 4
  for (int k = 0; k < DMODEL; k += 32) {
    bf16x8 af = frag8(xrow + k);
#pragma unroll
    for (int nb = 0; nb < 4; ++nb) {
      bf16x8 bfr = frag8(wbase + (size_t)nb * 16 * DMODEL + k);
      acc[nb] = __builtin_amdgcn_mfma_f32_16x16x32_bf16(af, bfr, acc[nb], 0, 0, 0);
    }
  }

#pragma unroll
  for (int nb = 0; nb < 4; ++nb) {
    const int n = ntile + nb * 16 + l16;
    const float bv = bias[n];
#pragma unroll
    for (int r = 0; r < 4; ++r) {
      const int m = m0 + g * 4 + r;
      float vv = acc[nb][r] + bv;
      size_t addr;
      if (mode == 0) {            // head-split [b*H+h][s][dk]
        int b = m >> 12, s = m & (S_LEN - 1);
        int h = n >> 6, d = n & 63;
        addr = (((size_t)(b * NH + h) * S_LEN) + s) * DK + d;
      } else if (mode == 2) {     // V transposed [b*H+h][dk][s]
        int b = m >> 12, s = m & (S_LEN - 1);
        int h = n >> 6, d = n & 63;
        addr = (((size_t)(b * NH + h) * DK) + d) * S_LEN + s;
      } else {                    // plain [m][n]
        addr = (size_t)m * DMODEL + n;
      }
      out[addr] = (TO)vv;
    }
  }
}

// ---------------------------------------------------------------------------
// Flash attention, swapped operands. Grid: (S/64, B*H). Block 256 = 4 waves,
// each wave independent, 16 q-rows.
//
// QK^T swapped: mfma(A=K_frag, B=Q_frag) -> C[kv_local = g*4+r][q = l16].
// Lane (g,l16) holds 16 scores, ALL for q-row l16 -> softmax is in-register:
// 15 fmax + 2 shfl_xor (masks 16,32) for max, same for sum; m/l/alpha are
// lane-local scalars.
// P redistributed via per-wave LDS [q=16][kv=64 (+4 pad)]: bf16x4 writes at
// [l16][nb*16+g*4], b128 reads at [l16][ks*32+g*8].
// PV swapped: mfma(A=V^T_frag, B=P_frag) -> O^T: o[db] reg r = O[q=l16][d=
// db*16+g*4+r]; rescale by lane-local alpha.
// ---------------------------------------------------------------------------
__global__ __launch_bounds__(256) void attn_kernel(
    const bf16_t* __restrict__ Qh, const bf16_t* __restrict__ Kh,
    const bf16_t* __restrict__ Vt, bf16_t* __restrict__ ctx)
{
  const int bh = blockIdx.y;                 // b*H + h
  const int b = bh >> 3, h = bh & 7;
  const int qbase = blockIdx.x * 64;
  const int wave = threadIdx.x >> 6;
  const int lane = threadIdx.x & 63;
  const int l16 = lane & 15;
  const int g = lane >> 4;                   // 0..3

  const bf16_t* Qp = Qh + (size_t)bh * S_LEN * DK;
  const bf16_t* Kp = Kh + (size_t)bh * S_LEN * DK;
  const bf16_t* Vp = Vt + (size_t)bh * DK * S_LEN;

  const int qrow0 = qbase + wave * 16;

  // Q fragment (B operand): row = l16 (q), k = ks*32 + g*8 + j. Pre-scaled.
  bf16x8 qf[2];
#pragma unroll
  for (int ks = 0; ks < 2; ++ks) {
    bf16x8 t = *reinterpret_cast<const bf16x8*>(
        Qp + (size_t)(qrow0 + l16) * DK + ks * 32 + g * 8);
#pragma unroll
    for (int j = 0; j < 8; ++j) t[j] = (__bf16)((float)t[j] * 0.125f);
    qf[ks] = t;
  }

  f32x4 o[4];                                // O^T: o[db][r] = O[q=l16][db*16+g*4+r]
#pragma unroll
  for (int db = 0; db < 4; ++db) o[db] = (f32x4){0.f, 0.f, 0.f, 0.f};
  float m_run = -1e30f, l_run = 0.f;         // lane-local (q = l16)

  __shared__ bf16_t pshare[4][16][68];       // per-wave P [q][kv], +4 pad

#pragma unroll 2
  for (int kv = 0; kv < S_LEN; kv += 64) {
    // ---- scores S^T: sc[nb] reg r = S[kv + nb*16 + g*4 + r][q = l16] ----
    f32x4 sc[4];
#pragma unroll
    for (int nb = 0; nb < 4; ++nb) {
      f32x4 a = (f32x4){0.f, 0.f, 0.f, 0.f};
#pragma unroll
      for (int ks = 0; ks < 2; ++ks) {
        bf16x8 kf = *reinterpret_cast<const bf16x8*>(
            Kp + (size_t)(kv + nb * 16 + l16) * DK + ks * 32 + g * 8);
        a = __builtin_amdgcn_mfma_f32_16x16x32_bf16(kf, qf[ks], a, 0, 0, 0);
      }
      sc[nb] = a;
    }

    // ---- online softmax, lane-local for q = l16 ----
    float vmax = sc[0][0];
#pragma unroll
    for (int nb = 0; nb < 4; ++nb)
#pragma unroll
      for (int r = 0; r < 4; ++r) vmax = fmaxf(vmax, sc[nb][r]);
    vmax = fmaxf(vmax, __shfl_xor(vmax, 16));
    vmax = fmaxf(vmax, __shfl_xor(vmax, 32));
    const float mnew = fmaxf(m_run, vmax);
    const float alpha = __expf(m_run - mnew);
    m_run = mnew;

    float psum = 0.f;
#pragma unroll
    for (int nb = 0; nb < 4; ++nb) {
      bf16x4 pw;
#pragma unroll
      for (int r = 0; r < 4; ++r) {
        const float p = __expf(sc[nb][r] - mnew);
        psum += p;
        pw[r] = (__bf16)p;
      }
      *reinterpret_cast<bf16x4*>(&pshare[wave][l16][nb * 16 + g * 4]) = pw;
    }
    psum += __shfl_xor(psum, 16);
    psum += __shfl_xor(psum, 32);
    l_run = l_run * alpha + psum;
#pragma unroll
    for (int db = 0; db < 4; ++db)
#pragma unroll
      for (int r = 0; r < 4; ++r) o[db][r] *= alpha;
    // no __syncthreads: pshare is per-wave; per-wave DS ordering suffices.

    // ---- PV swapped: A = V^T rows (d), B = P rows (q) ----
#pragma unroll
    for (int ks = 0; ks < 2; ++ks) {
      bf16x8 pf = *reinterpret_cast<const bf16x8*>(
          &pshare[wave][l16][ks * 32 + g * 8]);
#pragma unroll
      for (int db = 0; db < 4; ++db) {
        bf16x8 vf = *reinterpret_cast<const bf16x8*>(
            Vp + (size_t)(db * 16 + l16) * S_LEN + kv + ks * 32 + g * 8);
        o[db] = __builtin_amdgcn_mfma_f32_16x16x32_bf16(vf, pf, o[db], 0, 0, 0);
      }
    }
  }

  // ---- epilogue: O^T -> ctx[b][s=qrow0+l16][h*64 + db*16+g*4+r] ----
  const float inv_l = 1.f / l_run;
  bf16_t* crow = ctx + (((size_t)(b * S_LEN + qrow0 + l16)) * NH + h) * DK;
#pragma unroll
  for (int db = 0; db < 4; ++db) {
    bf16x4 cw;
#pragma unroll
    for (int r = 0; r < 4; ++r) cw[r] = (__bf16)(o[db][r] * inv_l);
    *reinterpret_cast<bf16x4*>(crow + db * 16 + g * 4) = cw;
  }
}

// ---------------------------------------------------------------------------
extern "C" void kernel_launch(void* const* d_in, const int* in_sizes, int n_in,
                              void* d_out, int out_size, void* d_ws, size_t ws_size,
                              hipStream_t stream)
{
  const float* q   = (const float*)d_in[0];
  const float* k   = (const float*)d_in[1];
  const float* v   = (const float*)d_in[2];
  const float* w_q = (const float*)d_in[3];
  const float* b_q = (const float*)d_in[4];
  const float* w_k = (const float*)d_in[5];
  const float* b_k = (const float*)d_in[6];
  const float* w_v = (const float*)d_in[7];
  const float* b_v = (const float*)d_in[8];
  const float* w_o = (const float*)d_in[9];
  const float* b_o = (const float*)d_in[10];
  float* out = (float*)d_out;

  char* ws = (char*)d_ws;
  const size_t sz = (size_t)NB * NH * S_LEN * DK * sizeof(bf16_t);  // 8 MiB each
  const size_t wsz = (size_t)DMODEL * DMODEL * sizeof(bf16_t);      // 512 KiB each
  bf16_t* Qh  = (bf16_t*)(ws);
  bf16_t* Kh  = (bf16_t*)(ws + sz);
  bf16_t* Vt  = (bf16_t*)(ws + 2 * sz);
  bf16_t* ctx = (bf16_t*)(ws + 3 * sz);
  bf16_t* Wq  = (bf16_t*)(ws + 4 * sz);
  bf16_t* Wk  = (bf16_t*)(ws + 4 * sz + wsz);
  bf16_t* Wv  = (bf16_t*)(ws + 4 * sz + 2 * wsz);
  bf16_t* Wo  = (bf16_t*)(ws + 4 * sz + 3 * wsz);

  cvt_weights<<<dim3(256, 4), 256, 0, stream>>>(w_q, w_k, w_v, w_o, Wq, Wk, Wv, Wo);

  dim3 gg(128, 8), bb(256);
  gemm_proj<float, bf16_t><<<gg, bb, 0, stream>>>(q, Wq, b_q, Qh, 0);
  gemm_proj<float, bf16_t><<<gg, bb, 0, stream>>>(k, Wk, b_k, Kh, 0);
  gemm_proj<float, bf16_t><<<gg, bb, 0, stream>>>(v, Wv, b_v, Vt, 2);
  attn_kernel<<<dim3(S_LEN / 64, NB * NH), bb, 0, stream>>>(Qh, Kh, Vt, ctx);
  gemm_proj<bf16_t, float><<<gg, bb, 0, stream>>>(ctx, Wo, b_o, out, 1);
}

// Round 6
// 295.108 us; speedup vs baseline: 2.5170x; 2.5170x over previous
//
#include <hip/hip_runtime.h>
#include <hip/hip_bf16.h>

// MultiHeadAttentionBlock: B=2, S=4096, D=512, H=8, DK=64.
// fp32 in/out, bf16 MFMA compute, fp32 accumulation.
// cvt weights->bf16; 3x proj GEMM (Q,K head-split; V transposed);
// flash attention: 8-wave block, QB=128 rows, KV tile 64 staged in LDS via
// global_load_lds (dbuf, 1 barrier/tile, source-XOR-swizzled vs read-swizzle),
// swapped-operand QK^T/PV (lane-local softmax); out proj.

typedef __bf16 bf16_t;
typedef __bf16 bf16x8 __attribute__((ext_vector_type(8)));
typedef __bf16 bf16x4 __attribute__((ext_vector_type(4)));
typedef float f32x4 __attribute__((ext_vector_type(4)));

#define S_LEN 4096
#define NH 8
#define DK 64
#define DMODEL 512
#define NB 2
#define KVB 64
#define QB 128

__device__ inline bf16x8 frag8(const bf16_t* p) {
  return *reinterpret_cast<const bf16x8*>(p);
}
__device__ inline bf16x8 frag8(const float* p) {
  f32x4 a = *reinterpret_cast<const f32x4*>(p);
  f32x4 b = *reinterpret_cast<const f32x4*>(p + 4);
  bf16x8 r;
#pragma unroll
  for (int j = 0; j < 4; ++j) { r[j] = (__bf16)a[j]; r[j + 4] = (__bf16)b[j]; }
  return r;
}

__device__ inline void gload_lds16(const void* g, void* l) {
  __builtin_amdgcn_global_load_lds(
      (const __attribute__((address_space(1))) unsigned int*)g,
      (__attribute__((address_space(3))) unsigned int*)l, 16, 0, 0);
}

// ---------------------------------------------------------------------------
// One-time fp32 -> bf16 weight conversion. grid (256, 4), 4 elems/thread.
// ---------------------------------------------------------------------------
__global__ __launch_bounds__(256) void cvt_weights(
    const float* __restrict__ w0, const float* __restrict__ w1,
    const float* __restrict__ w2, const float* __restrict__ w3,
    bf16_t* __restrict__ o0, bf16_t* __restrict__ o1,
    bf16_t* __restrict__ o2, bf16_t* __restrict__ o3)
{
  const float* src = blockIdx.y == 0 ? w0 : blockIdx.y == 1 ? w1
                   : blockIdx.y == 2 ? w2 : w3;
  bf16_t* dst = blockIdx.y == 0 ? o0 : blockIdx.y == 1 ? o1
              : blockIdx.y == 2 ? o2 : o3;
  const int i = (blockIdx.x * 256 + threadIdx.x) * 4;
  f32x4 v = *reinterpret_cast<const f32x4*>(src + i);
  bf16x4 r;
#pragma unroll
  for (int j = 0; j < 4; ++j) r[j] = (__bf16)v[j];
  *reinterpret_cast<bf16x4*>(dst + i) = r;
}

// ---------------------------------------------------------------------------
// GEMM: out[m][n] = sum_k X[m][k] * W[n][k] + bias[n]
// M=8192, N=512, K=512. Tile 64x64/block, wave -> 16(m) x 64(n). W pre-cvt bf16.
// mode 0: out [B*H][S][DK]; mode 2: [B*H][DK][S] (V transposed); mode 1: [m][n].
// ---------------------------------------------------------------------------
template <typename TA, typename TO>
__global__ __launch_bounds__(256) void gemm_proj(
    const TA* __restrict__ X, const bf16_t* __restrict__ W,
    const float* __restrict__ bias, TO* __restrict__ out, int mode)
{
  const int mtile = blockIdx.x * 64;
  const int ntile = blockIdx.y * 64;
  const int wave = threadIdx.x >> 6;
  const int lane = threadIdx.x & 63;
  const int l16 = lane & 15;
  const int g = lane >> 4;
  const int m0 = mtile + wave * 16;

  f32x4 acc[4];
#pragma unroll
  for (int nb = 0; nb < 4; ++nb) acc[nb] = (f32x4){0.f, 0.f, 0.f, 0.f};

  const TA* xrow = X + (size_t)(m0 + l16) * DMODEL + g * 8;
  const bf16_t* wbase = W + (size_t)(ntile + l16) * DMODEL + g * 8;

#pragma unroll 4
  for (int k = 0; k < DMODEL; k += 32) {
    bf16x8 af = frag8(xrow + k);
#pragma unroll
    for (int nb = 0; nb < 4; ++nb) {
      bf16x8 bfr = frag8(wbase + (size_t)nb * 16 * DMODEL + k);
      acc[nb] = __builtin_amdgcn_mfma_f32_16x16x32_bf16(af, bfr, acc[nb], 0, 0, 0);
    }
  }

#pragma unroll
  for (int nb = 0; nb < 4; ++nb) {
    const int n = ntile + nb * 16 + l16;
    const float bv = bias[n];
#pragma unroll
    for (int r = 0; r < 4; ++r) {
      const int m = m0 + g * 4 + r;
      float vv = acc[nb][r] + bv;
      size_t addr;
      if (mode == 0) {            // head-split [b*H+h][s][dk]
        int b = m >> 12, s = m & (S_LEN - 1);
        int h = n >> 6, d = n & 63;
        addr = (((size_t)(b * NH + h) * S_LEN) + s) * DK + d;
      } else if (mode == 2) {     // V transposed [b*H+h][dk][s]
        int b = m >> 12, s = m & (S_LEN - 1);
        int h = n >> 6, d = n & 63;
        addr = (((size_t)(b * NH + h) * DK) + d) * S_LEN + s;
      } else {                    // plain [m][n]
        addr = (size_t)m * DMODEL + n;
      }
      out[addr] = (TO)vv;
    }
  }
}

// ---------------------------------------------------------------------------
// Flash attention, 8-wave block, LDS-staged K/V.
// Grid: flat 512 blocks; xcd = wg&7 serves heads {2*xcd, 2*xcd+1} (dispatch is
// round-robin across 8 XCDs -> per-XCD K/V working set = 2 MB < 4 MB L2).
// head = (wg&7)*2 + ((wg>>3)&1), qtile = wg>>4 (32 q-tiles of 128 rows).
//
// Per tile: K [64 kv][64 dk] and V^T [64 d][64 kv] staged to LDS by
// global_load_lds (wave w stages rows 8w..8w+7; LDS dest wave-uniform base +
// lane*16, linear). SOURCE 16B-slot is XOR'd by row&7; reads XOR the same ->
// LDS[row][c] = global[row][c ^ (row&7)], so stride-128B ds_read_b128 is
// 2-way (free) instead of 16-way. Double-buffered; prefetch t+1 at loop head;
// one __syncthreads per tile (its vmcnt(0) drain finishes the prefetch).
//
// QK^T swapped: mfma(A=K, B=Q) -> lane (g,l16) holds 16 scores all for q-row
// l16 -> softmax lane-local (15 fmax + 2 shfl_xor for max; same for sum).
// P via per-wave LDS [q=16][kv=64+4 pad]. PV swapped: mfma(A=V^T, B=P) -> O^T.
// ---------------------------------------------------------------------------
__global__ __launch_bounds__(512) void attn_kernel(
    const bf16_t* __restrict__ Qh, const bf16_t* __restrict__ Kh,
    const bf16_t* __restrict__ Vt, bf16_t* __restrict__ ctx)
{
  const int wg = blockIdx.x;
  const int bh = (wg & 7) * 2 + ((wg >> 3) & 1);
  const int qtile = wg >> 4;
  const int b = bh >> 3, h = bh & 7;
  const int wave = threadIdx.x >> 6;         // 0..7
  const int lane = threadIdx.x & 63;
  const int l16 = lane & 15;
  const int g = lane >> 4;                   // 0..3

  __shared__ bf16_t ldsK[2][KVB][64];        // 8 KB per buf
  __shared__ bf16_t ldsV[2][KVB][64];        // V^T tile: [d][kv]
  __shared__ bf16_t pshare[8][16][68];       // per-wave P, padded rows

  const bf16_t* Qp = Qh + (size_t)bh * S_LEN * DK;
  const bf16_t* Kp = Kh + (size_t)bh * S_LEN * DK;
  const bf16_t* Vp = Vt + (size_t)bh * DK * S_LEN;

  const int qrow0 = qtile * QB + wave * 16;

  // staging geometry: this thread feeds row srow (of 8 per wave), slot scol16
  const int srow = 8 * wave + (lane >> 3);        // tile row 0..63
  const int scol16 = (lane & 7) ^ (lane >> 3);    // XOR-swizzled source 16B slot
  const char* Ksrc = (const char*)Kp + (size_t)srow * 128 + scol16 * 16;
  const char* Vsrc = (const char*)Vp + (size_t)srow * (S_LEN * 2) + scol16 * 16;

  // Q fragment (B operand): row = l16 (q), k = ks*32 + g*8 + j. Pre-scaled.
  bf16x8 qf[2];
#pragma unroll
  for (int ks = 0; ks < 2; ++ks) {
    bf16x8 t = *reinterpret_cast<const bf16x8*>(
        Qp + (size_t)(qrow0 + l16) * DK + ks * 32 + g * 8);
#pragma unroll
    for (int j = 0; j < 8; ++j) t[j] = (__bf16)((float)t[j] * 0.125f);
    qf[ks] = t;
  }

  f32x4 o[4];                                // O^T: o[db][r] = O[q=l16][db*16+g*4+r]
#pragma unroll
  for (int db = 0; db < 4; ++db) o[db] = (f32x4){0.f, 0.f, 0.f, 0.f};
  float m_run = -1e30f, l_run = 0.f;         // lane-local (q = l16)

  const int rxor = (l16 & 7) << 4;           // read-side XOR (row&7)<<4 bytes

  // prologue: stage tile 0 into buf 0
  gload_lds16(Ksrc, (char*)&ldsK[0][8 * wave][0]);
  gload_lds16(Vsrc, (char*)&ldsV[0][8 * wave][0]);
  __syncthreads();

  const int NT = S_LEN / KVB;                // 64
  int buf = 0;
  for (int t = 0; t < NT; ++t) {
    // prefetch next tile into the other buffer (overlaps with compute below)
    if (t + 1 < NT) {
      const size_t koff = (size_t)(t + 1) * KVB * 128;      // bytes
      const size_t voff = (size_t)(t + 1) * KVB * 2;        // bytes
      gload_lds16(Ksrc + koff, (char*)&ldsK[buf ^ 1][8 * wave][0]);
      gload_lds16(Vsrc + voff, (char*)&ldsV[buf ^ 1][8 * wave][0]);
    }

    // ---- scores S^T: sc[nb] reg r = S[kv + nb*16 + g*4 + r][q = l16] ----
    f32x4 sc[4];
#pragma unroll
    for (int nb = 0; nb < 4; ++nb) {
      f32x4 a = (f32x4){0.f, 0.f, 0.f, 0.f};
#pragma unroll
      for (int ks = 0; ks < 2; ++ks) {
        const int row = nb * 16 + l16;
        bf16x8 kf = *reinterpret_cast<const bf16x8*>(
            (const char*)&ldsK[buf][0][0] + row * 128 + ((ks * 64 + g * 16) ^ rxor));
        a = __builtin_amdgcn_mfma_f32_16x16x32_bf16(kf, qf[ks], a, 0, 0, 0);
      }
      sc[nb] = a;
    }

    // ---- online softmax, lane-local for q = l16 ----
    float vmax = sc[0][0];
#pragma unroll
    for (int nb = 0; nb < 4; ++nb)
#pragma unroll
      for (int r = 0; r < 4; ++r) vmax = fmaxf(vmax, sc[nb][r]);
    vmax = fmaxf(vmax, __shfl_xor(vmax, 16));
    vmax = fmaxf(vmax, __shfl_xor(vmax, 32));
    const float mnew = fmaxf(m_run, vmax);
    const float alpha = __expf(m_run - mnew);
    m_run = mnew;

    float psum = 0.f;
#pragma unroll
    for (int nb = 0; nb < 4; ++nb) {
      bf16x4 pw;
#pragma unroll
      for (int r = 0; r < 4; ++r) {
        const float p = __expf(sc[nb][r] - mnew);
        psum += p;
        pw[r] = (__bf16)p;
      }
      *reinterpret_cast<bf16x4*>(&pshare[wave][l16][nb * 16 + g * 4]) = pw;
    }
    psum += __shfl_xor(psum, 16);
    psum += __shfl_xor(psum, 32);
    l_run = l_run * alpha + psum;
#pragma unroll
    for (int db = 0; db < 4; ++db)
#pragma unroll
      for (int r = 0; r < 4; ++r) o[db][r] *= alpha;

    // ---- PV swapped: A = V^T rows (d) from LDS, B = P rows (q) ----
#pragma unroll
    for (int ks = 0; ks < 2; ++ks) {
      bf16x8 pf = *reinterpret_cast<const bf16x8*>(
          &pshare[wave][l16][ks * 32 + g * 8]);
#pragma unroll
      for (int db = 0; db < 4; ++db) {
        const int row = db * 16 + l16;       // d
        bf16x8 vf = *reinterpret_cast<const bf16x8*>(
            (const char*)&ldsV[buf][0][0] + row * 128 + ((ks * 64 + g * 16) ^ rxor));
        o[db] = __builtin_amdgcn_mfma_f32_16x16x32_bf16(vf, pf, o[db], 0, 0, 0);
      }
    }

    // one barrier/tile: implicit vmcnt(0) finishes the prefetch; also ensures
    // all waves are done reading buf before it's overwritten next iteration.
    __syncthreads();
    buf ^= 1;
  }

  // ---- epilogue: O^T -> ctx[b][s=qrow0+l16][h*64 + db*16+g*4+r] ----
  const float inv_l = 1.f / l_run;
  bf16_t* crow = ctx + (((size_t)(b * S_LEN + qrow0 + l16)) * NH + h) * DK;
#pragma unroll
  for (int db = 0; db < 4; ++db) {
    bf16x4 cw;
#pragma unroll
    for (int r = 0; r < 4; ++r) cw[r] = (__bf16)(o[db][r] * inv_l);
    *reinterpret_cast<bf16x4*>(crow + db * 16 + g * 4) = cw;
  }
}

// ---------------------------------------------------------------------------
extern "C" void kernel_launch(void* const* d_in, const int* in_sizes, int n_in,
                              void* d_out, int out_size, void* d_ws, size_t ws_size,
                              hipStream_t stream)
{
  const float* q   = (const float*)d_in[0];
  const float* k   = (const float*)d_in[1];
  const float* v   = (const float*)d_in[2];
  const float* w_q = (const float*)d_in[3];
  const float* b_q = (const float*)d_in[4];
  const float* w_k = (const float*)d_in[5];
  const float* b_k = (const float*)d_in[6];
  const float* w_v = (const float*)d_in[7];
  const float* b_v = (const float*)d_in[8];
  const float* w_o = (const float*)d_in[9];
  const float* b_o = (const float*)d_in[10];
  float* out = (float*)d_out;

  char* ws = (char*)d_ws;
  const size_t sz = (size_t)NB * NH * S_LEN * DK * sizeof(bf16_t);  // 8 MiB each
  const size_t wsz = (size_t)DMODEL * DMODEL * sizeof(bf16_t);      // 512 KiB each
  bf16_t* Qh  = (bf16_t*)(ws);
  bf16_t* Kh  = (bf16_t*)(ws + sz);
  bf16_t* Vt  = (bf16_t*)(ws + 2 * sz);
  bf16_t* ctx = (bf16_t*)(ws + 3 * sz);
  bf16_t* Wq  = (bf16_t*)(ws + 4 * sz);
  bf16_t* Wk  = (bf16_t*)(ws + 4 * sz + wsz);
  bf16_t* Wv  = (bf16_t*)(ws + 4 * sz + 2 * wsz);
  bf16_t* Wo  = (bf16_t*)(ws + 4 * sz + 3 * wsz);

  cvt_weights<<<dim3(256, 4), 256, 0, stream>>>(w_q, w_k, w_v, w_o, Wq, Wk, Wv, Wo);

  dim3 gg(128, 8), bb(256);
  gemm_proj<float, bf16_t><<<gg, bb, 0, stream>>>(q, Wq, b_q, Qh, 0);
  gemm_proj<float, bf16_t><<<gg, bb, 0, stream>>>(k, Wk, b_k, Kh, 0);
  gemm_proj<float, bf16_t><<<gg, bb, 0, stream>>>(v, Wv, b_v, Vt, 2);
  attn_kernel<<<dim3(512), dim3(512), 0, stream>>>(Qh, Kh, Vt, ctx);
  gemm_proj<bf16_t, float><<<gg, bb, 0, stream>>>(ctx, Wo, b_o, out, 1);
}

// Round 7
// 185.610 us; speedup vs baseline: 4.0018x; 1.5899x over previous
//
#include <hip/hip_runtime.h>
#include <hip/hip_bf16.h>

// MultiHeadAttentionBlock: B=2, S=4096, D=512, H=8, DK=64.
// fp32 in/out, bf16 MFMA compute, fp32 accumulation.
// cvt inputs+weights->bf16; 4x staged GEMM (LDS dbuf via global_load_lds,
// XOR-swizzled); flash attention (8-wave, LDS-staged K/V, swapped-operand,
// lane-local softmax).

typedef __bf16 bf16_t;
typedef __bf16 bf16x8 __attribute__((ext_vector_type(8)));
typedef __bf16 bf16x4 __attribute__((ext_vector_type(4)));
typedef float f32x4 __attribute__((ext_vector_type(4)));

#define S_LEN 4096
#define NH 8
#define DK 64
#define DMODEL 512
#define NB 2
#define KVB 64
#define QB 128

__device__ inline void gload_lds16(const void* g, void* l) {
  __builtin_amdgcn_global_load_lds(
      (const __attribute__((address_space(1))) unsigned int*)g,
      (__attribute__((address_space(3))) unsigned int*)l, 16, 0, 0);
}

// ---------------------------------------------------------------------------
// fp32 -> bf16 conversions. cvt_x: one 8192x512 tensor, 8 elems/thread.
// ---------------------------------------------------------------------------
__global__ __launch_bounds__(256) void cvt_x(
    const float* __restrict__ src, bf16_t* __restrict__ dst)
{
  const int i = (blockIdx.x * 256 + threadIdx.x) * 8;
  f32x4 a = *reinterpret_cast<const f32x4*>(src + i);
  f32x4 b = *reinterpret_cast<const f32x4*>(src + i + 4);
  bf16x8 r;
#pragma unroll
  for (int j = 0; j < 4; ++j) { r[j] = (__bf16)a[j]; r[j + 4] = (__bf16)b[j]; }
  *reinterpret_cast<bf16x8*>(dst + i) = r;
}

__global__ __launch_bounds__(256) void cvt_weights(
    const float* __restrict__ w0, const float* __restrict__ w1,
    const float* __restrict__ w2, const float* __restrict__ w3,
    bf16_t* __restrict__ o0, bf16_t* __restrict__ o1,
    bf16_t* __restrict__ o2, bf16_t* __restrict__ o3)
{
  const float* src = blockIdx.y == 0 ? w0 : blockIdx.y == 1 ? w1
                   : blockIdx.y == 2 ? w2 : w3;
  bf16_t* dst = blockIdx.y == 0 ? o0 : blockIdx.y == 1 ? o1
              : blockIdx.y == 2 ? o2 : o3;
  const int i = (blockIdx.x * 256 + threadIdx.x) * 4;
  f32x4 v = *reinterpret_cast<const f32x4*>(src + i);
  bf16x4 r;
#pragma unroll
  for (int j = 0; j < 4; ++j) r[j] = (__bf16)v[j];
  *reinterpret_cast<bf16x4*>(dst + i) = r;
}

// ---------------------------------------------------------------------------
// Staged GEMM: out[m][n] = sum_k A[m][k] * W[n][k] + bias[n]. All bf16 in.
// M=8192, N=512, K=512. Tile 64x64, BK=64, 4 waves (wave w: m-rows 16w..16w+15,
// all 64 n). A/B tiles staged to LDS via global_load_lds (2 calls each per
// K-step; wave covers 8 rows/call). Source 16B-slot XOR'd by row&7; fragment
// reads XOR the same -> stride-128B ds_read_b128 is 2-way (free).
// Double-buffered; prefetch at loop head; one __syncthreads per K-step.
// mode 0: out [B*H][S][DK]; mode 2: [B*H][DK][S] (V transposed); mode 1: [m][n].
// ---------------------------------------------------------------------------
template <typename TO>
__global__ __launch_bounds__(256) void gemm_tile(
    const bf16_t* __restrict__ A, const bf16_t* __restrict__ W,
    const float* __restrict__ bias, TO* __restrict__ out, int mode)
{
  const int mtile = blockIdx.x * 64;
  const int ntile = blockIdx.y * 64;
  const int wave = threadIdx.x >> 6;
  const int lane = threadIdx.x & 63;
  const int l16 = lane & 15;
  const int g = lane >> 4;

  __shared__ bf16_t ldsA[2][64][64];   // 8 KB per buf
  __shared__ bf16_t ldsB[2][64][64];

  // staging geometry (identical scheme to attn): per call the wave covers
  // rows 8w..8w+7; thread's row = 8w + (lane>>3), source slot (lane&7)^(row&7)
  const int srow = 8 * wave + (lane >> 3);
  const int sslot = (lane & 7) ^ ((lane >> 3) & 7);
  const char* Asrc = (const char*)A + ((size_t)(mtile + srow) * DMODEL) * 2 + sslot * 16;
  const char* Bsrc = (const char*)W + ((size_t)(ntile + srow) * DMODEL) * 2 + sslot * 16;
  const size_t rblk = (size_t)32 * DMODEL * 2;   // +32 rows

  f32x4 acc[4];
#pragma unroll
  for (int nb = 0; nb < 4; ++nb) acc[nb] = (f32x4){0.f, 0.f, 0.f, 0.f};

  const int rxor = (l16 & 7) << 4;     // read-side XOR: (row&7)*16 bytes

  // prologue: stage K-step 0 into buf 0
  gload_lds16(Asrc, (char*)&ldsA[0][8 * wave][0]);
  gload_lds16(Asrc + rblk, (char*)&ldsA[0][32 + 8 * wave][0]);
  gload_lds16(Bsrc, (char*)&ldsB[0][8 * wave][0]);
  gload_lds16(Bsrc + rblk, (char*)&ldsB[0][32 + 8 * wave][0]);
  __syncthreads();

  const int NSTEP = DMODEL / 64;       // 8
  int buf = 0;
  for (int t = 0; t < NSTEP; ++t) {
    if (t + 1 < NSTEP) {
      const size_t ko = (size_t)(t + 1) * 128;   // 64 k-elems = 128 B
      gload_lds16(Asrc + ko, (char*)&ldsA[buf ^ 1][8 * wave][0]);
      gload_lds16(Asrc + rblk + ko, (char*)&ldsA[buf ^ 1][32 + 8 * wave][0]);
      gload_lds16(Bsrc + ko, (char*)&ldsB[buf ^ 1][8 * wave][0]);
      gload_lds16(Bsrc + rblk + ko, (char*)&ldsB[buf ^ 1][32 + 8 * wave][0]);
    }

#pragma unroll
    for (int ks = 0; ks < 2; ++ks) {
      const int arow = 16 * wave + l16;
      bf16x8 af = *reinterpret_cast<const bf16x8*>(
          (const char*)&ldsA[buf][0][0] + arow * 128 + ((ks * 64 + g * 16) ^ rxor));
#pragma unroll
      for (int nb = 0; nb < 4; ++nb) {
        const int brow = nb * 16 + l16;
        bf16x8 bfr = *reinterpret_cast<const bf16x8*>(
            (const char*)&ldsB[buf][0][0] + brow * 128 + ((ks * 64 + g * 16) ^ rxor));
        acc[nb] = __builtin_amdgcn_mfma_f32_16x16x32_bf16(af, bfr, acc[nb], 0, 0, 0);
      }
    }

    __syncthreads();                   // drains prefetch (vmcnt0) + guards buf
    buf ^= 1;
  }

  const int m0 = mtile + wave * 16;
#pragma unroll
  for (int nb = 0; nb < 4; ++nb) {
    const int n = ntile + nb * 16 + l16;
    const float bv = bias[n];
#pragma unroll
    for (int r = 0; r < 4; ++r) {
      const int m = m0 + g * 4 + r;
      float vv = acc[nb][r] + bv;
      size_t addr;
      if (mode == 0) {            // head-split [b*H+h][s][dk]
        int b = m >> 12, s = m & (S_LEN - 1);
        int h = n >> 6, d = n & 63;
        addr = (((size_t)(b * NH + h) * S_LEN) + s) * DK + d;
      } else if (mode == 2) {     // V transposed [b*H+h][dk][s]
        int b = m >> 12, s = m & (S_LEN - 1);
        int h = n >> 6, d = n & 63;
        addr = (((size_t)(b * NH + h) * DK) + d) * S_LEN + s;
      } else {                    // plain [m][n]
        addr = (size_t)m * DMODEL + n;
      }
      out[addr] = (TO)vv;
    }
  }
}

// ---------------------------------------------------------------------------
// Flash attention, 8-wave block, LDS-staged K/V (unchanged from round 6).
// ---------------------------------------------------------------------------
__global__ __launch_bounds__(512) void attn_kernel(
    const bf16_t* __restrict__ Qh, const bf16_t* __restrict__ Kh,
    const bf16_t* __restrict__ Vt, bf16_t* __restrict__ ctx)
{
  const int wg = blockIdx.x;
  const int bh = (wg & 7) * 2 + ((wg >> 3) & 1);
  const int qtile = wg >> 4;
  const int b = bh >> 3, h = bh & 7;
  const int wave = threadIdx.x >> 6;         // 0..7
  const int lane = threadIdx.x & 63;
  const int l16 = lane & 15;
  const int g = lane >> 4;                   // 0..3

  __shared__ bf16_t ldsK[2][KVB][64];
  __shared__ bf16_t ldsV[2][KVB][64];        // V^T tile: [d][kv]
  __shared__ bf16_t pshare[8][16][68];       // per-wave P, padded rows

  const bf16_t* Qp = Qh + (size_t)bh * S_LEN * DK;
  const bf16_t* Kp = Kh + (size_t)bh * S_LEN * DK;
  const bf16_t* Vp = Vt + (size_t)bh * DK * S_LEN;

  const int qrow0 = qtile * QB + wave * 16;

  const int srow = 8 * wave + (lane >> 3);
  const int scol16 = (lane & 7) ^ (lane >> 3);
  const char* Ksrc = (const char*)Kp + (size_t)srow * 128 + scol16 * 16;
  const char* Vsrc = (const char*)Vp + (size_t)srow * (S_LEN * 2) + scol16 * 16;

  bf16x8 qf[2];
#pragma unroll
  for (int ks = 0; ks < 2; ++ks) {
    bf16x8 t = *reinterpret_cast<const bf16x8*>(
        Qp + (size_t)(qrow0 + l16) * DK + ks * 32 + g * 8);
#pragma unroll
    for (int j = 0; j < 8; ++j) t[j] = (__bf16)((float)t[j] * 0.125f);
    qf[ks] = t;
  }

  f32x4 o[4];
#pragma unroll
  for (int db = 0; db < 4; ++db) o[db] = (f32x4){0.f, 0.f, 0.f, 0.f};
  float m_run = -1e30f, l_run = 0.f;

  const int rxor = (l16 & 7) << 4;

  gload_lds16(Ksrc, (char*)&ldsK[0][8 * wave][0]);
  gload_lds16(Vsrc, (char*)&ldsV[0][8 * wave][0]);
  __syncthreads();

  const int NT = S_LEN / KVB;                // 64
  int buf = 0;
  for (int t = 0; t < NT; ++t) {
    if (t + 1 < NT) {
      const size_t koff = (size_t)(t + 1) * KVB * 128;
      const size_t voff = (size_t)(t + 1) * KVB * 2;
      gload_lds16(Ksrc + koff, (char*)&ldsK[buf ^ 1][8 * wave][0]);
      gload_lds16(Vsrc + voff, (char*)&ldsV[buf ^ 1][8 * wave][0]);
    }

    f32x4 sc[4];
#pragma unroll
    for (int nb = 0; nb < 4; ++nb) {
      f32x4 a = (f32x4){0.f, 0.f, 0.f, 0.f};
#pragma unroll
      for (int ks = 0; ks < 2; ++ks) {
        const int row = nb * 16 + l16;
        bf16x8 kf = *reinterpret_cast<const bf16x8*>(
            (const char*)&ldsK[buf][0][0] + row * 128 + ((ks * 64 + g * 16) ^ rxor));
        a = __builtin_amdgcn_mfma_f32_16x16x32_bf16(kf, qf[ks], a, 0, 0, 0);
      }
      sc[nb] = a;
    }

    float vmax = sc[0][0];
#pragma unroll
    for (int nb = 0; nb < 4; ++nb)
#pragma unroll
      for (int r = 0; r < 4; ++r) vmax = fmaxf(vmax, sc[nb][r]);
    vmax = fmaxf(vmax, __shfl_xor(vmax, 16));
    vmax = fmaxf(vmax, __shfl_xor(vmax, 32));
    const float mnew = fmaxf(m_run, vmax);
    const float alpha = __expf(m_run - mnew);
    m_run = mnew;

    float psum = 0.f;
#pragma unroll
    for (int nb = 0; nb < 4; ++nb) {
      bf16x4 pw;
#pragma unroll
      for (int r = 0; r < 4; ++r) {
        const float p = __expf(sc[nb][r] - mnew);
        psum += p;
        pw[r] = (__bf16)p;
      }
      *reinterpret_cast<bf16x4*>(&pshare[wave][l16][nb * 16 + g * 4]) = pw;
    }
    psum += __shfl_xor(psum, 16);
    psum += __shfl_xor(psum, 32);
    l_run = l_run * alpha + psum;
#pragma unroll
    for (int db = 0; db < 4; ++db)
#pragma unroll
      for (int r = 0; r < 4; ++r) o[db][r] *= alpha;

#pragma unroll
    for (int ks = 0; ks < 2; ++ks) {
      bf16x8 pf = *reinterpret_cast<const bf16x8*>(
          &pshare[wave][l16][ks * 32 + g * 8]);
#pragma unroll
      for (int db = 0; db < 4; ++db) {
        const int row = db * 16 + l16;
        bf16x8 vf = *reinterpret_cast<const bf16x8*>(
            (const char*)&ldsV[buf][0][0] + row * 128 + ((ks * 64 + g * 16) ^ rxor));
        o[db] = __builtin_amdgcn_mfma_f32_16x16x32_bf16(vf, pf, o[db], 0, 0, 0);
      }
    }

    __syncthreads();
    buf ^= 1;
  }

  const float inv_l = 1.f / l_run;
  bf16_t* crow = ctx + (((size_t)(b * S_LEN + qrow0 + l16)) * NH + h) * DK;
#pragma unroll
  for (int db = 0; db < 4; ++db) {
    bf16x4 cw;
#pragma unroll
    for (int r = 0; r < 4; ++r) cw[r] = (__bf16)(o[db][r] * inv_l);
    *reinterpret_cast<bf16x4*>(crow + db * 16 + g * 4) = cw;
  }
}

// ---------------------------------------------------------------------------
extern "C" void kernel_launch(void* const* d_in, const int* in_sizes, int n_in,
                              void* d_out, int out_size, void* d_ws, size_t ws_size,
                              hipStream_t stream)
{
  const float* q   = (const float*)d_in[0];
  const float* k   = (const float*)d_in[1];
  const float* v   = (const float*)d_in[2];
  const float* w_q = (const float*)d_in[3];
  const float* b_q = (const float*)d_in[4];
  const float* w_k = (const float*)d_in[5];
  const float* b_k = (const float*)d_in[6];
  const float* w_v = (const float*)d_in[7];
  const float* b_v = (const float*)d_in[8];
  const float* w_o = (const float*)d_in[9];
  const float* b_o = (const float*)d_in[10];
  float* out = (float*)d_out;

  char* ws = (char*)d_ws;
  const size_t sz = (size_t)NB * NH * S_LEN * DK * sizeof(bf16_t);  // 8 MiB each
  const size_t wsz = (size_t)DMODEL * DMODEL * sizeof(bf16_t);      // 512 KiB each
  bf16_t* X   = (bf16_t*)(ws);            // bf16 input staging; later ctx
  bf16_t* Qh  = (bf16_t*)(ws + sz);
  bf16_t* Kh  = (bf16_t*)(ws + 2 * sz);
  bf16_t* Vt  = (bf16_t*)(ws + 3 * sz);
  bf16_t* Wq  = (bf16_t*)(ws + 4 * sz);
  bf16_t* Wk  = (bf16_t*)(ws + 4 * sz + wsz);
  bf16_t* Wv  = (bf16_t*)(ws + 4 * sz + 2 * wsz);
  bf16_t* Wo  = (bf16_t*)(ws + 4 * sz + 3 * wsz);

  cvt_weights<<<dim3(256, 4), 256, 0, stream>>>(w_q, w_k, w_v, w_o, Wq, Wk, Wv, Wo);

  const int cvtg = (NB * S_LEN * DMODEL) / (256 * 8);   // 2048
  dim3 gg(128, 8), bb(256);

  cvt_x<<<cvtg, 256, 0, stream>>>(q, X);
  gemm_tile<bf16_t><<<gg, bb, 0, stream>>>(X, Wq, b_q, Qh, 0);
  cvt_x<<<cvtg, 256, 0, stream>>>(k, X);
  gemm_tile<bf16_t><<<gg, bb, 0, stream>>>(X, Wk, b_k, Kh, 0);
  cvt_x<<<cvtg, 256, 0, stream>>>(v, X);
  gemm_tile<bf16_t><<<gg, bb, 0, stream>>>(X, Wv, b_v, Vt, 2);

  attn_kernel<<<dim3(512), dim3(512), 0, stream>>>(Qh, Kh, Vt, X /*ctx*/);

  gemm_tile<float><<<gg, bb, 0, stream>>>(X, Wo, b_o, out, 1);
}

// Round 9
// 173.090 us; speedup vs baseline: 4.2913x; 1.0723x over previous
//
#include <hip/hip_runtime.h>
#include <hip/hip_bf16.h>

// MultiHeadAttentionBlock: B=2, S=4096, D=512, H=8, DK=64.
// fp32 in/out, bf16 MFMA compute, fp32 accumulation.
// cvt inputs+weights->bf16; 4x staged GEMM (LDS dbuf via global_load_lds,
// XOR-swizzled); flash attention (8-wave, LDS-staged K/V, swapped-operand,
// lane-local softmax in exp2 domain, defer-max, setprio).

typedef __bf16 bf16_t;
typedef __bf16 bf16x8 __attribute__((ext_vector_type(8)));
typedef __bf16 bf16x4 __attribute__((ext_vector_type(4)));
typedef float f32x4 __attribute__((ext_vector_type(4)));

#define S_LEN 4096
#define NH 8
#define DK 64
#define DMODEL 512
#define NB 2
#define KVB 64
#define QB 128

#define EXP2F(x) __builtin_amdgcn_exp2f(x)   // v_exp_f32 (2^x); __exp2f clashes with glibc

__device__ inline void gload_lds16(const void* g, void* l) {
  __builtin_amdgcn_global_load_lds(
      (const __attribute__((address_space(1))) unsigned int*)g,
      (__attribute__((address_space(3))) unsigned int*)l, 16, 0, 0);
}

// ---------------------------------------------------------------------------
// fp32 -> bf16 conversions. cvt_x: one 8192x512 tensor, 8 elems/thread.
// ---------------------------------------------------------------------------
__global__ __launch_bounds__(256) void cvt_x(
    const float* __restrict__ src, bf16_t* __restrict__ dst)
{
  const int i = (blockIdx.x * 256 + threadIdx.x) * 8;
  f32x4 a = *reinterpret_cast<const f32x4*>(src + i);
  f32x4 b = *reinterpret_cast<const f32x4*>(src + i + 4);
  bf16x8 r;
#pragma unroll
  for (int j = 0; j < 4; ++j) { r[j] = (__bf16)a[j]; r[j + 4] = (__bf16)b[j]; }
  *reinterpret_cast<bf16x8*>(dst + i) = r;
}

__global__ __launch_bounds__(256) void cvt_weights(
    const float* __restrict__ w0, const float* __restrict__ w1,
    const float* __restrict__ w2, const float* __restrict__ w3,
    bf16_t* __restrict__ o0, bf16_t* __restrict__ o1,
    bf16_t* __restrict__ o2, bf16_t* __restrict__ o3)
{
  const float* src = blockIdx.y == 0 ? w0 : blockIdx.y == 1 ? w1
                   : blockIdx.y == 2 ? w2 : w3;
  bf16_t* dst = blockIdx.y == 0 ? o0 : blockIdx.y == 1 ? o1
              : blockIdx.y == 2 ? o2 : o3;
  const int i = (blockIdx.x * 256 + threadIdx.x) * 4;
  f32x4 v = *reinterpret_cast<const f32x4*>(src + i);
  bf16x4 r;
#pragma unroll
  for (int j = 0; j < 4; ++j) r[j] = (__bf16)v[j];
  *reinterpret_cast<bf16x4*>(dst + i) = r;
}

// ---------------------------------------------------------------------------
// Staged GEMM: out[m][n] = sum_k A[m][k] * W[n][k] + bias[n]. All bf16 in.
// M=8192, N=512, K=512. Tile 64x64, BK=64, 4 waves. A/B tiles staged to LDS
// via global_load_lds, source-XOR/read-XOR swizzled, double-buffered,
// one __syncthreads per K-step.
// mode 0: out [B*H][S][DK]; mode 2: [B*H][DK][S] (V transposed); mode 1: [m][n].
// ---------------------------------------------------------------------------
template <typename TO>
__global__ __launch_bounds__(256) void gemm_tile(
    const bf16_t* __restrict__ A, const bf16_t* __restrict__ W,
    const float* __restrict__ bias, TO* __restrict__ out, int mode)
{
  const int mtile = blockIdx.x * 64;
  const int ntile = blockIdx.y * 64;
  const int wave = threadIdx.x >> 6;
  const int lane = threadIdx.x & 63;
  const int l16 = lane & 15;
  const int g = lane >> 4;

  __shared__ bf16_t ldsA[2][64][64];   // 8 KB per buf
  __shared__ bf16_t ldsB[2][64][64];

  const int srow = 8 * wave + (lane >> 3);
  const int sslot = (lane & 7) ^ ((lane >> 3) & 7);
  const char* Asrc = (const char*)A + ((size_t)(mtile + srow) * DMODEL) * 2 + sslot * 16;
  const char* Bsrc = (const char*)W + ((size_t)(ntile + srow) * DMODEL) * 2 + sslot * 16;
  const size_t rblk = (size_t)32 * DMODEL * 2;   // +32 rows

  f32x4 acc[4];
#pragma unroll
  for (int nb = 0; nb < 4; ++nb) acc[nb] = (f32x4){0.f, 0.f, 0.f, 0.f};

  const int rxor = (l16 & 7) << 4;     // read-side XOR: (row&7)*16 bytes

  gload_lds16(Asrc, (char*)&ldsA[0][8 * wave][0]);
  gload_lds16(Asrc + rblk, (char*)&ldsA[0][32 + 8 * wave][0]);
  gload_lds16(Bsrc, (char*)&ldsB[0][8 * wave][0]);
  gload_lds16(Bsrc + rblk, (char*)&ldsB[0][32 + 8 * wave][0]);
  __syncthreads();

  const int NSTEP = DMODEL / 64;       // 8
  int buf = 0;
  for (int t = 0; t < NSTEP; ++t) {
    if (t + 1 < NSTEP) {
      const size_t ko = (size_t)(t + 1) * 128;   // 64 k-elems = 128 B
      gload_lds16(Asrc + ko, (char*)&ldsA[buf ^ 1][8 * wave][0]);
      gload_lds16(Asrc + rblk + ko, (char*)&ldsA[buf ^ 1][32 + 8 * wave][0]);
      gload_lds16(Bsrc + ko, (char*)&ldsB[buf ^ 1][8 * wave][0]);
      gload_lds16(Bsrc + rblk + ko, (char*)&ldsB[buf ^ 1][32 + 8 * wave][0]);
    }

#pragma unroll
    for (int ks = 0; ks < 2; ++ks) {
      const int arow = 16 * wave + l16;
      bf16x8 af = *reinterpret_cast<const bf16x8*>(
          (const char*)&ldsA[buf][0][0] + arow * 128 + ((ks * 64 + g * 16) ^ rxor));
#pragma unroll
      for (int nb = 0; nb < 4; ++nb) {
        const int brow = nb * 16 + l16;
        bf16x8 bfr = *reinterpret_cast<const bf16x8*>(
            (const char*)&ldsB[buf][0][0] + brow * 128 + ((ks * 64 + g * 16) ^ rxor));
        acc[nb] = __builtin_amdgcn_mfma_f32_16x16x32_bf16(af, bfr, acc[nb], 0, 0, 0);
      }
    }

    __syncthreads();                   // drains prefetch (vmcnt0) + guards buf
    buf ^= 1;
  }

  const int m0 = mtile + wave * 16;
#pragma unroll
  for (int nb = 0; nb < 4; ++nb) {
    const int n = ntile + nb * 16 + l16;
    const float bv = bias[n];
#pragma unroll
    for (int r = 0; r < 4; ++r) {
      const int m = m0 + g * 4 + r;
      float vv = acc[nb][r] + bv;
      size_t addr;
      if (mode == 0) {            // head-split [b*H+h][s][dk]
        int b = m >> 12, s = m & (S_LEN - 1);
        int h = n >> 6, d = n & 63;
        addr = (((size_t)(b * NH + h) * S_LEN) + s) * DK + d;
      } else if (mode == 2) {     // V transposed [b*H+h][dk][s]
        int b = m >> 12, s = m & (S_LEN - 1);
        int h = n >> 6, d = n & 63;
        addr = (((size_t)(b * NH + h) * DK) + d) * S_LEN + s;
      } else {                    // plain [m][n]
        addr = (size_t)m * DMODEL + n;
      }
      out[addr] = (TO)vv;
    }
  }
}

// ---------------------------------------------------------------------------
// Flash attention, 8-wave block, LDS-staged K/V.
// Round-9 deltas (all local): softmax in exp2 domain (log2e folded into the
// Q pre-scale; p = v_exp_f32 directly, no per-element mul); T13 defer-max
// (skip alpha/O-rescale while __all(vmax - m_run <= 8), P bounded by 2^8);
// T5 s_setprio(1) around the MFMA clusters.
// ---------------------------------------------------------------------------
__global__ __launch_bounds__(512) void attn_kernel(
    const bf16_t* __restrict__ Qh, const bf16_t* __restrict__ Kh,
    const bf16_t* __restrict__ Vt, bf16_t* __restrict__ ctx)
{
  const int wg = blockIdx.x;
  const int bh = (wg & 7) * 2 + ((wg >> 3) & 1);
  const int qtile = wg >> 4;
  const int b = bh >> 3, h = bh & 7;
  const int wave = threadIdx.x >> 6;         // 0..7
  const int lane = threadIdx.x & 63;
  const int l16 = lane & 15;
  const int g = lane >> 4;                   // 0..3

  __shared__ bf16_t ldsK[2][KVB][64];
  __shared__ bf16_t ldsV[2][KVB][64];        // V^T tile: [d][kv]
  __shared__ bf16_t pshare[8][16][68];       // per-wave P, padded rows

  const bf16_t* Qp = Qh + (size_t)bh * S_LEN * DK;
  const bf16_t* Kp = Kh + (size_t)bh * S_LEN * DK;
  const bf16_t* Vp = Vt + (size_t)bh * DK * S_LEN;

  const int qrow0 = qtile * QB + wave * 16;

  const int srow = 8 * wave + (lane >> 3);
  const int scol16 = (lane & 7) ^ (lane >> 3);
  const char* Ksrc = (const char*)Kp + (size_t)srow * 128 + scol16 * 16;
  const char* Vsrc = (const char*)Vp + (size_t)srow * (S_LEN * 2) + scol16 * 16;

  // Q fragment, pre-scaled by (1/sqrt(DK)) * log2(e) -> scores in log2 units
  const float qscale = 0.125f * 1.44269504089f;
  bf16x8 qf[2];
#pragma unroll
  for (int ks = 0; ks < 2; ++ks) {
    bf16x8 t = *reinterpret_cast<const bf16x8*>(
        Qp + (size_t)(qrow0 + l16) * DK + ks * 32 + g * 8);
#pragma unroll
    for (int j = 0; j < 8; ++j) t[j] = (__bf16)((float)t[j] * qscale);
    qf[ks] = t;
  }

  f32x4 o[4];
#pragma unroll
  for (int db = 0; db < 4; ++db) o[db] = (f32x4){0.f, 0.f, 0.f, 0.f};
  float m_run = -1e30f, l_run = 0.f;

  const int rxor = (l16 & 7) << 4;

  gload_lds16(Ksrc, (char*)&ldsK[0][8 * wave][0]);
  gload_lds16(Vsrc, (char*)&ldsV[0][8 * wave][0]);
  __syncthreads();

  const int NT = S_LEN / KVB;                // 64
  int buf = 0;
  for (int t = 0; t < NT; ++t) {
    if (t + 1 < NT) {
      const size_t koff = (size_t)(t + 1) * KVB * 128;
      const size_t voff = (size_t)(t + 1) * KVB * 2;
      gload_lds16(Ksrc + koff, (char*)&ldsK[buf ^ 1][8 * wave][0]);
      gload_lds16(Vsrc + voff, (char*)&ldsV[buf ^ 1][8 * wave][0]);
    }

    // ---- scores S^T (log2 units) ----
    f32x4 sc[4];
    __builtin_amdgcn_s_setprio(1);
#pragma unroll
    for (int nb = 0; nb < 4; ++nb) {
      f32x4 a = (f32x4){0.f, 0.f, 0.f, 0.f};
#pragma unroll
      for (int ks = 0; ks < 2; ++ks) {
        const int row = nb * 16 + l16;
        bf16x8 kf = *reinterpret_cast<const bf16x8*>(
            (const char*)&ldsK[buf][0][0] + row * 128 + ((ks * 64 + g * 16) ^ rxor));
        a = __builtin_amdgcn_mfma_f32_16x16x32_bf16(kf, qf[ks], a, 0, 0, 0);
      }
      sc[nb] = a;
    }
    __builtin_amdgcn_s_setprio(0);

    // ---- online softmax in exp2 domain, lane-local for q = l16 ----
    float vmax = sc[0][0];
#pragma unroll
    for (int nb = 0; nb < 4; ++nb)
#pragma unroll
      for (int r = 0; r < 4; ++r) vmax = fmaxf(vmax, sc[nb][r]);
    vmax = fmaxf(vmax, __shfl_xor(vmax, 16));
    vmax = fmaxf(vmax, __shfl_xor(vmax, 32));

    // T13 defer-max: only rescale when some row's max grew past THR=8
    if (!__all(vmax - m_run <= 8.0f)) {
      const float mnew = fmaxf(m_run, vmax);
      const float alpha = EXP2F(m_run - mnew);
      m_run = mnew;
      l_run *= alpha;
#pragma unroll
      for (int db = 0; db < 4; ++db)
#pragma unroll
        for (int r = 0; r < 4; ++r) o[db][r] *= alpha;
    }

    float psum = 0.f;
#pragma unroll
    for (int nb = 0; nb < 4; ++nb) {
      bf16x4 pw;
#pragma unroll
      for (int r = 0; r < 4; ++r) {
        const float p = EXP2F(sc[nb][r] - m_run);
        psum += p;
        pw[r] = (__bf16)p;
      }
      *reinterpret_cast<bf16x4*>(&pshare[wave][l16][nb * 16 + g * 4]) = pw;
    }
    psum += __shfl_xor(psum, 16);
    psum += __shfl_xor(psum, 32);
    l_run += psum;

    // ---- PV swapped: A = V^T rows (d) from LDS, B = P rows (q) ----
    __builtin_amdgcn_s_setprio(1);
#pragma unroll
    for (int ks = 0; ks < 2; ++ks) {
      bf16x8 pf = *reinterpret_cast<const bf16x8*>(
          &pshare[wave][l16][ks * 32 + g * 8]);
#pragma unroll
      for (int db = 0; db < 4; ++db) {
        const int row = db * 16 + l16;
        bf16x8 vf = *reinterpret_cast<const bf16x8*>(
            (const char*)&ldsV[buf][0][0] + row * 128 + ((ks * 64 + g * 16) ^ rxor));
        o[db] = __builtin_amdgcn_mfma_f32_16x16x32_bf16(vf, pf, o[db], 0, 0, 0);
      }
    }
    __builtin_amdgcn_s_setprio(0);

    __syncthreads();
    buf ^= 1;
  }

  const float inv_l = 1.f / l_run;
  bf16_t* crow = ctx + (((size_t)(b * S_LEN + qrow0 + l16)) * NH + h) * DK;
#pragma unroll
  for (int db = 0; db < 4; ++db) {
    bf16x4 cw;
#pragma unroll
    for (int r = 0; r < 4; ++r) cw[r] = (__bf16)(o[db][r] * inv_l);
    *reinterpret_cast<bf16x4*>(crow + db * 16 + g * 4) = cw;
  }
}

// ---------------------------------------------------------------------------
extern "C" void kernel_launch(void* const* d_in, const int* in_sizes, int n_in,
                              void* d_out, int out_size, void* d_ws, size_t ws_size,
                              hipStream_t stream)
{
  const float* q   = (const float*)d_in[0];
  const float* k   = (const float*)d_in[1];
  const float* v   = (const float*)d_in[2];
  const float* w_q = (const float*)d_in[3];
  const float* b_q = (const float*)d_in[4];
  const float* w_k = (const float*)d_in[5];
  const float* b_k = (const float*)d_in[6];
  const float* w_v = (const float*)d_in[7];
  const float* b_v = (const float*)d_in[8];
  const float* w_o = (const float*)d_in[9];
  const float* b_o = (const float*)d_in[10];
  float* out = (float*)d_out;

  char* ws = (char*)d_ws;
  const size_t sz = (size_t)NB * NH * S_LEN * DK * sizeof(bf16_t);  // 8 MiB each
  const size_t wsz = (size_t)DMODEL * DMODEL * sizeof(bf16_t);      // 512 KiB each
  bf16_t* X   = (bf16_t*)(ws);            // bf16 input staging; later ctx
  bf16_t* Qh  = (bf16_t*)(ws + sz);
  bf16_t* Kh  = (bf16_t*)(ws + 2 * sz);
  bf16_t* Vt  = (bf16_t*)(ws + 3 * sz);
  bf16_t* Wq  = (bf16_t*)(ws + 4 * sz);
  bf16_t* Wk  = (bf16_t*)(ws + 4 * sz + wsz);
  bf16_t* Wv  = (bf16_t*)(ws + 4 * sz + 2 * wsz);
  bf16_t* Wo  = (bf16_t*)(ws + 4 * sz + 3 * wsz);

  cvt_weights<<<dim3(256, 4), 256, 0, stream>>>(w_q, w_k, w_v, w_o, Wq, Wk, Wv, Wo);

  const int cvtg = (NB * S_LEN * DMODEL) / (256 * 8);   // 2048
  dim3 gg(128, 8), bb(256);

  cvt_x<<<cvtg, 256, 0, stream>>>(q, X);
  gemm_tile<bf16_t><<<gg, bb, 0, stream>>>(X, Wq, b_q, Qh, 0);
  cvt_x<<<cvtg, 256, 0, stream>>>(k, X);
  gemm_tile<bf16_t><<<gg, bb, 0, stream>>>(X, Wk, b_k, Kh, 0);
  cvt_x<<<cvtg, 256, 0, stream>>>(v, X);
  gemm_tile<bf16_t><<<gg, bb, 0, stream>>>(X, Wv, b_v, Vt, 2);

  attn_kernel<<<dim3(512), dim3(512), 0, stream>>>(Qh, Kh, Vt, X /*ctx*/);

  gemm_tile<float><<<gg, bb, 0, stream>>>(X, Wo, b_o, out, 1);
}